// Round 14
// baseline (248.826 us; speedup 1.0000x reference)
//
#include <hip/hip_runtime.h>
#include <cmath>

// ---------------------------------------------------------------------------
// StructuralAttentionLayer on MI355X (gfx950)
// N=50000, E=800000, D=128, H=8, DK=16
// Round 21: revert R20 (per-block weight conversion +16us on scatter_qkv —
// amortize-once prep beats convert-per-block; VGPR 68->76 and 96 scalar
// stride-512B loads/lane repeated 782x). Restore R19 prep-kernel form
// (proven 236.3). Experiment riding the revert: qkv blocks FIRST, scatter
// blocks LAST in the merged dispatch — R19 WRITE 58MB vs 29MB payload =
// slot-line re-writebacks from qkv streaming evictions; tail-concentrated
// scatter should collect writes with less competing traffic.
// Ledger: no nt hints (R17/R18); no per-block weight conversion (R20);
// amortized prep + cnt zeroing (no memset dispatch).
// Carried: slotted scatter, XCD-binned stores, swizzled GEMM staging,
// fused FFN (h1 in LDS), fp8 K/V, packed-f32 attn.
// ---------------------------------------------------------------------------

typedef short v8s __attribute__((ext_vector_type(8)));   // 8 bf16 (4 VGPRs)
typedef float v4f __attribute__((ext_vector_type(4)));   // 4 fp32 acc
typedef float v2f __attribute__((ext_vector_type(2)));

__device__ __forceinline__ float gelu_exact(float x) {
    return 0.5f * x * (1.0f + erff(x * 0.70710678118654752440f));
}

__device__ __forceinline__ unsigned short f2bf(float f) {
    unsigned int u = __float_as_uint(f);
    u = (u + 0x7fffu + ((u >> 16) & 1u)) >> 16;
    return (unsigned short)u;
}

__device__ __forceinline__ float2 bf2_to_f2(unsigned int u) {
    float2 r;
    r.x = __uint_as_float(u << 16);
    r.y = __uint_as_float(u & 0xffff0000u);
    return r;
}

__device__ __forceinline__ unsigned char f2fp8(float f) {
    unsigned int p = __builtin_amdgcn_cvt_pk_fp8_f32(f, f, 0, false);
    return (unsigned char)(p & 0xffu);
}

// per-edge attention accumulate, packed-f32 (q pre-scaled by 1/sqrt(dk))
__device__ __forceinline__ void edge_accum(uint4 k4, uint4 v4, bool ok,
                                           const v2f (&qv)[8],
                                           v2f (&acc)[8], float& sml) {
    v2f f;
    v2f da = (v2f){0.f, 0.f}, db = (v2f){0.f, 0.f};
    f = __builtin_amdgcn_cvt_pk_f32_fp8(k4.x, false); da = __builtin_elementwise_fma(f, qv[0], da);
    f = __builtin_amdgcn_cvt_pk_f32_fp8(k4.x, true);  db = __builtin_elementwise_fma(f, qv[1], db);
    f = __builtin_amdgcn_cvt_pk_f32_fp8(k4.y, false); da = __builtin_elementwise_fma(f, qv[2], da);
    f = __builtin_amdgcn_cvt_pk_f32_fp8(k4.y, true);  db = __builtin_elementwise_fma(f, qv[3], db);
    f = __builtin_amdgcn_cvt_pk_f32_fp8(k4.z, false); da = __builtin_elementwise_fma(f, qv[4], da);
    f = __builtin_amdgcn_cvt_pk_f32_fp8(k4.z, true);  db = __builtin_elementwise_fma(f, qv[5], db);
    f = __builtin_amdgcn_cvt_pk_f32_fp8(k4.w, false); da = __builtin_elementwise_fma(f, qv[6], da);
    f = __builtin_amdgcn_cvt_pk_f32_fp8(k4.w, true);  db = __builtin_elementwise_fma(f, qv[7], db);
    float dot = (da[0] + db[0]) + (da[1] + db[1]);
    float pe = ok ? __expf(dot) : 0.f;
    sml += pe;
    v2f pv = (v2f){pe, pe};
    f = __builtin_amdgcn_cvt_pk_f32_fp8(v4.x, false); acc[0] = __builtin_elementwise_fma(pv, f, acc[0]);
    f = __builtin_amdgcn_cvt_pk_f32_fp8(v4.x, true);  acc[1] = __builtin_elementwise_fma(pv, f, acc[1]);
    f = __builtin_amdgcn_cvt_pk_f32_fp8(v4.y, false); acc[2] = __builtin_elementwise_fma(pv, f, acc[2]);
    f = __builtin_amdgcn_cvt_pk_f32_fp8(v4.y, true);  acc[3] = __builtin_elementwise_fma(pv, f, acc[3]);
    f = __builtin_amdgcn_cvt_pk_f32_fp8(v4.z, false); acc[4] = __builtin_elementwise_fma(pv, f, acc[4]);
    f = __builtin_amdgcn_cvt_pk_f32_fp8(v4.z, true);  acc[5] = __builtin_elementwise_fma(pv, f, acc[5]);
    f = __builtin_amdgcn_cvt_pk_f32_fp8(v4.w, false); acc[6] = __builtin_elementwise_fma(pv, f, acc[6]);
    f = __builtin_amdgcn_cvt_pk_f32_fp8(v4.w, true);  acc[7] = __builtin_elementwise_fma(pv, f, acc[7]);
}

// ---- weight prep + cnt zeroing ---------------------------------------------

__global__ __launch_bounds__(256)
void prep_kernel(const float* __restrict__ Wq, const float* __restrict__ Wk,
                 const float* __restrict__ Wv, const float* __restrict__ W1,
                 const float* __restrict__ W2,
                 const float* __restrict__ bq, const float* __restrict__ bk,
                 const float* __restrict__ bv, const float* __restrict__ b1,
                 const float* __restrict__ b2,
                 unsigned short* __restrict__ wcat, unsigned short* __restrict__ w1t,
                 unsigned short* __restrict__ w2t, float* __restrict__ bcat,
                 int* __restrict__ cnt, int n) {
    int i = blockIdx.x * 256 + threadIdx.x;
    if (i < n) cnt[i] = 0;
    if (i < 49152) {                       // 3 x 128x128: Wt[c][k] = W[k][c]
        int m = i >> 14, j = i & 16383;
        int c = j >> 7, k = j & 127;
        const float* W = (m == 0) ? Wq : (m == 1) ? Wk : Wv;
        wcat[i] = f2bf(W[k * 128 + c]);
    } else if (i < 49152 + 32768) {        // W1: [256 cols x 128 k]
        int j = i - 49152;
        int c = j >> 7, k = j & 127;
        w1t[j] = f2bf(W1[k * 256 + c]);
    } else if (i < 49152 + 65536) {        // W2: [128 cols x 256 k]
        int j = i - 49152 - 32768;
        int c = j >> 8, k = j & 255;
        w2t[j] = f2bf(W2[k * 128 + c]);
    } else if (i < 49152 + 65536 + 768) {
        int j = i - 49152 - 65536;
        float v;
        if (j < 128)      v = bq[j];
        else if (j < 256) v = bk[j - 128];
        else if (j < 384) v = bv[j - 256];
        else if (j < 640) v = b1[j - 384];
        else              v = b2[j - 640];
        bcat[j] = v;
    }
}

// ---- merged QKV GEMM + scatter (qkv blocks FIRST, scatter in tail) ---------
// Blocks [0, nqkv): fused QKV projection. Blocks [nqkv, nqkv+nscat):
// XCD-binned slotted scatter — runs tail-concentrated so slot lines collect
// their ~16 writes with minimal competing qkv stream traffic in L2.

__global__ __launch_bounds__(512)
void scatter_qkv_kernel(const float* __restrict__ A,
                        const unsigned short* __restrict__ wcat,
                        const float* __restrict__ bcat,
                        unsigned short* __restrict__ qb,
                        unsigned char* __restrict__ kvh,
                        int n_rows,
                        const int* __restrict__ src, const int* __restrict__ dst,
                        int* __restrict__ cnt, int* __restrict__ slots,
                        int E, int nseg, int nbpr, int nqkv) {
    __shared__ unsigned short Xs[8192];   // 16 KB, swizzled [64][16 chunks]

    if ((int)blockIdx.x >= nqkv) {
        // scatter: r = blockIdx.x & 7 == physical XCD (round-robin);
        // (r, b) unique since nscat % 8 == 0 over a contiguous index range.
        const int r = blockIdx.x & 7;
        const int b = (blockIdx.x - nqkv) >> 3;
        const int lo = r * nseg, hi = lo + nseg;
        const int stride = nbpr * 512;
        const int E4 = E >> 2;
        for (int i = b * 512 + threadIdx.x; i < E4; i += stride) {
            int4 d4 = ((const int4*)dst)[i];
            int4 s4 = ((const int4*)src)[i];
            if (d4.x >= lo && d4.x < hi) { int p = atomicAdd(&cnt[d4.x], 1); if (p < 64) slots[(d4.x << 6) + p] = s4.x; }
            if (d4.y >= lo && d4.y < hi) { int p = atomicAdd(&cnt[d4.y], 1); if (p < 64) slots[(d4.y << 6) + p] = s4.y; }
            if (d4.z >= lo && d4.z < hi) { int p = atomicAdd(&cnt[d4.z], 1); if (p < 64) slots[(d4.z << 6) + p] = s4.z; }
            if (d4.w >= lo && d4.w < hi) { int p = atomicAdd(&cnt[d4.w], 1); if (p < 64) slots[(d4.w << 6) + p] = s4.w; }
        }
        if (b == 0) {
            for (int e = (E4 << 2) + threadIdx.x; e < E; e += 512) {
                int d = dst[e];
                if (d >= lo && d < hi) {
                    int p = atomicAdd(&cnt[d], 1);
                    if (p < 64) slots[(d << 6) + p] = src[e];
                }
            }
        }
        return;
    }

    const int t = threadIdx.x;
    const int l = t & 63;
    const int w = t >> 6;           // wave 0..7 -> output cols [w*16, w*16+16)
    const int lq = l >> 4;          // quarter 0..3
    const int lc = l & 15;
    const int rb = blockIdx.x * 64;

    #pragma unroll
    for (int it = 0; it < 2; ++it) {
        int idx = it * 512 + t;             // 0..1023 v8s slots
        int row = idx >> 4, ch = idx & 15;
        v8s av = (v8s){0, 0, 0, 0, 0, 0, 0, 0};
        if (rb + row < n_rows) {
            const float* ap = &A[(size_t)(rb + row) * 128 + ch * 8];
            float4 f0 = *(const float4*)ap;
            float4 f1 = *(const float4*)(ap + 4);
            av[0] = (short)f2bf(f0.x); av[1] = (short)f2bf(f0.y);
            av[2] = (short)f2bf(f0.z); av[3] = (short)f2bf(f0.w);
            av[4] = (short)f2bf(f1.x); av[5] = (short)f2bf(f1.y);
            av[6] = (short)f2bf(f1.z); av[7] = (short)f2bf(f1.w);
        }
        *(v8s*)&Xs[row * 128 + ((ch ^ (row & 7)) * 8)] = av;
    }
    __syncthreads();

    v8s a[4][4];
    #pragma unroll
    for (int c = 0; c < 4; ++c)
        #pragma unroll
        for (int i = 0; i < 4; ++i)
            a[c][i] = *(const v8s*)&Xs[(i * 16 + lc) * 128 +
                                       (((c * 4 + lq) ^ (lc & 7)) * 8)];

    const int col = w * 16 + lc;
    #pragma unroll
    for (int y = 0; y < 3; ++y) {
        const unsigned short* Bt = wcat + y * 16384;
        v8s bf[4];
        #pragma unroll
        for (int c = 0; c < 4; ++c)
            bf[c] = *(const v8s*)&Bt[(size_t)col * 128 + c * 32 + lq * 8];

        v4f acc[4];
        #pragma unroll
        for (int i = 0; i < 4; ++i) acc[i] = (v4f){0.f, 0.f, 0.f, 0.f};
        #pragma unroll
        for (int c = 0; c < 4; ++c)
            #pragma unroll
            for (int i = 0; i < 4; ++i)
                acc[i] = __builtin_amdgcn_mfma_f32_16x16x32_bf16(a[c][i], bf[c], acc[i], 0, 0, 0);

        float bi = bcat[y * 128 + col];
        #pragma unroll
        for (int i = 0; i < 4; ++i) {
            #pragma unroll
            for (int reg = 0; reg < 4; ++reg) {
                int rr = rb + i * 16 + lq * 4 + reg;
                if (rr >= n_rows) continue;
                float vv = acc[i][reg] + bi;
                if (y == 0)
                    qb[(size_t)rr * 128 + col] = f2bf(vv);
                else
                    kvh[(size_t)rr * 256 + w * 32 + lc + (y == 2 ? 16 : 0)] = f2fp8(vv);
            }
        }
    }
}

// ---- Attention + residual + LayerNorm --------------------------------------

__global__ __launch_bounds__(256)
void attn_ln_kernel(const unsigned short* __restrict__ q,
                    const unsigned char* __restrict__ kvh,
                    const float* __restrict__ x,
                    const int* __restrict__ cnt, const int* __restrict__ slots,
                    const float* __restrict__ ln_g, const float* __restrict__ ln_b,
                    float* __restrict__ hb, unsigned short* __restrict__ hnb,
                    int n) {
    const int wave = threadIdx.x >> 6;
    const int lane = threadIdx.x & 63;
    const int node = blockIdx.x * 4 + wave;
    if (node >= n) return;
    const int head = lane & 7;
    const int slot = lane >> 3;

    const unsigned int* qp = (const unsigned int*)&q[(size_t)node * 128 + head * 16];
    v2f qv[8];
    #pragma unroll
    for (int i = 0; i < 8; ++i) {
        float2 r = bf2_to_f2(qp[i]);
        qv[i] = (v2f){r.x * 0.25f, r.y * 0.25f};
    }

    const int e0 = node << 6;
    const int e1 = e0 + min(cnt[node], 64);

    float sml = 0.f;
    v2f acc[8];
    #pragma unroll
    for (int i = 0; i < 8; ++i) acc[i] = (v2f){0.f, 0.f};

    if (e1 > e0) {
        const int elast = e1 - 1;
        for (int j = e0; j < e1; j += 16) {
            int ea = j + slot;
            int eb = ea + 8;
            bool oka = ea < e1;
            bool okb = eb < e1;
            int sa = slots[oka ? ea : elast];
            int sb = slots[okb ? eb : elast];
            const uint4* kpa = (const uint4*)&kvh[(size_t)sa * 256 + head * 32];
            const uint4* kpb = (const uint4*)&kvh[(size_t)sb * 256 + head * 32];
            uint4 ka  = kpa[0];
            uint4 va4 = kpa[1];
            uint4 kb  = kpb[0];
            uint4 vb4 = kpb[1];
            edge_accum(ka, va4, oka, qv, acc, sml);
            edge_accum(kb, vb4, okb, qv, acc, sml);
        }
    }

    // reduce-scatter butterfly over slot bits (lane bits 3,4,5)
    const bool b0 = (slot & 1) != 0, b1 = (slot & 2) != 0, b2 = (slot & 4) != 0;
    v2f k0[4];
    #pragma unroll
    for (int j = 0; j < 4; ++j) {
        v2f snd = b0 ? acc[2 * j] : acc[2 * j + 1];
        v2f kp  = b0 ? acc[2 * j + 1] : acc[2 * j];
        snd[0] = __shfl_xor(snd[0], 8, 64);
        snd[1] = __shfl_xor(snd[1], 8, 64);
        k0[j] = kp + snd;
    }
    v2f k1[2];
    #pragma unroll
    for (int j = 0; j < 2; ++j) {
        v2f snd = b1 ? k0[2 * j] : k0[2 * j + 1];
        v2f kp  = b1 ? k0[2 * j + 1] : k0[2 * j];
        snd[0] = __shfl_xor(snd[0], 16, 64);
        snd[1] = __shfl_xor(snd[1], 16, 64);
        k1[j] = kp + snd;
    }
    {
        v2f snd = b2 ? k1[0] : k1[1];
        v2f kp  = b2 ? k1[1] : k1[0];
        snd[0] = __shfl_xor(snd[0], 32, 64);
        snd[1] = __shfl_xor(snd[1], 32, 64);
        k1[0] = kp + snd;
    }
    v2f o = k1[0];

    sml += __shfl_xor(sml, 8, 64);
    sml += __shfl_xor(sml, 16, 64);
    sml += __shfl_xor(sml, 32, 64);

    float inv = 1.f / (sml + 1e-16f);

    const int d = head * 16 + slot * 2;
    float2 xv = *(const float2*)&x[(size_t)node * 128 + d];
    float2 hv = make_float2(o[0] * inv + xv.x, o[1] * inv + xv.y);
    *(float2*)&hb[(size_t)node * 128 + d] = hv;

    float s  = hv.x + hv.y;
    float s2 = hv.x * hv.x + hv.y * hv.y;
    #pragma unroll
    for (int off = 1; off < 64; off <<= 1) {
        s  += __shfl_xor(s, off, 64);
        s2 += __shfl_xor(s2, off, 64);
    }
    float mu  = s * (1.f / 128.f);
    float var = s2 * (1.f / 128.f) - mu * mu;
    float rstd = rsqrtf(var + 1e-5f);
    float2 gv = *(const float2*)&ln_g[d];
    float2 bv = *(const float2*)&ln_b[d];
    ushort2 ob;
    ob.x = f2bf((hv.x - mu) * rstd * gv.x + bv.x);
    ob.y = f2bf((hv.y - mu) * rstd * gv.y + bv.y);
    *(ushort2*)&hnb[(size_t)node * 128 + d] = ob;
}

// ---- fused FFN: out = hb + W2t^T . gelu(W1t^T . hn + b1) + b2 --------------

__global__ __launch_bounds__(512)
void ffn_fused_kernel(const unsigned short* __restrict__ hnb,
                      const unsigned short* __restrict__ w1t,
                      const unsigned short* __restrict__ w2t,
                      const float* __restrict__ bcat,
                      const float* __restrict__ hb,
                      float* __restrict__ out, int n_rows) {
    __shared__ unsigned short As[8192];    // hn tile [64][128] bf16, 16 KB
    __shared__ unsigned short H1[16384];   // h1 tile [64][256] bf16, 32 KB

    const int t = threadIdx.x;
    const int l = t & 63;
    const int w = t >> 6;
    const int lq = l >> 4;
    const int lc = l & 15;
    const int rb = blockIdx.x * 64;

    // stage hn tile coalesced -> swizzled LDS
    #pragma unroll
    for (int it = 0; it < 2; ++it) {
        int idx = it * 512 + t;
        int row = idx >> 4, ch = idx & 15;
        v8s av = (v8s){0, 0, 0, 0, 0, 0, 0, 0};
        if (rb + row < n_rows)
            av = *(const v8s*)&hnb[(size_t)(rb + row) * 128 + ch * 8];
        *(v8s*)&As[row * 128 + ((ch ^ (row & 7)) * 8)] = av;
    }

    // B1 frags for this wave's 32 mids (issued before barrier: overlaps stage)
    v8s b1f[2][4];
    #pragma unroll
    for (int j = 0; j < 2; ++j)
        #pragma unroll
        for (int c = 0; c < 4; ++c) {
            int colm = w * 32 + j * 16 + lc;
            b1f[j][c] = *(const v8s*)&w1t[(size_t)colm * 128 + c * 32 + lq * 8];
        }
    __syncthreads();

    // ---- GEMM1: 64 rows x 32 mids ----
    v4f acc1[4][2];
    #pragma unroll
    for (int i = 0; i < 4; ++i)
        #pragma unroll
        for (int j = 0; j < 2; ++j)
            acc1[i][j] = (v4f){0.f, 0.f, 0.f, 0.f};

    #pragma unroll
    for (int c = 0; c < 4; ++c) {
        v8s a[4];
        #pragma unroll
        for (int i = 0; i < 4; ++i)
            a[i] = *(const v8s*)&As[(i * 16 + lc) * 128 +
                                    (((c * 4 + lq) ^ (lc & 7)) * 8)];
        #pragma unroll
        for (int i = 0; i < 4; ++i)
            #pragma unroll
            for (int j = 0; j < 2; ++j)
                acc1[i][j] = __builtin_amdgcn_mfma_f32_16x16x32_bf16(a[i], b1f[j][c], acc1[i][j], 0, 0, 0);
    }

    // bias + gelu -> h1 LDS (swizzled scalar bf16 writes)
    #pragma unroll
    for (int j = 0; j < 2; ++j) {
        int colm = w * 32 + j * 16 + lc;
        float bi = bcat[384 + colm];
        int ch = colm >> 3;
        #pragma unroll
        for (int i = 0; i < 4; ++i) {
            #pragma unroll
            for (int reg = 0; reg < 4; ++reg) {
                int r = i * 16 + lq * 4 + reg;
                float vv = gelu_exact(acc1[i][j][reg] + bi);
                H1[r * 256 + ((ch ^ (r & 7)) * 8) + (colm & 7)] = f2bf(vv);
            }
        }
    }

    // B2 frags for this wave's 16 out cols (issue before barrier)
    const int col = w * 16 + lc;
    v8s b2f[8];
    #pragma unroll
    for (int c = 0; c < 8; ++c)
        b2f[c] = *(const v8s*)&w2t[(size_t)col * 256 + c * 32 + lq * 8];
    __syncthreads();

    // ---- GEMM2: 64 rows x 16 cols, K=256 from h1 LDS ----
    v4f acc2[4];
    #pragma unroll
    for (int i = 0; i < 4; ++i) acc2[i] = (v4f){0.f, 0.f, 0.f, 0.f};

    #pragma unroll
    for (int c = 0; c < 8; ++c) {
        #pragma unroll
        for (int i = 0; i < 4; ++i) {
            v8s a = *(const v8s*)&H1[(i * 16 + lc) * 256 +
                                     (((c * 4 + lq) ^ (lc & 7)) * 8)];
            acc2[i] = __builtin_amdgcn_mfma_f32_16x16x32_bf16(a, b2f[c], acc2[i], 0, 0, 0);
        }
    }

    float bi2 = bcat[640 + col];
    #pragma unroll
    for (int i = 0; i < 4; ++i) {
        #pragma unroll
        for (int reg = 0; reg < 4; ++reg) {
            int rr = rb + i * 16 + lq * 4 + reg;
            if (rr >= n_rows) continue;
            out[(size_t)rr * 128 + col] =
                acc2[i][reg] + bi2 + hb[(size_t)rr * 128 + col];
        }
    }
}

// ---------------------------------------------------------------------------

extern "C" void kernel_launch(void* const* d_in, const int* in_sizes, int n_in,
                              void* d_out, int out_size, void* d_ws, size_t ws_size,
                              hipStream_t stream) {
    const float* x    = (const float*)d_in[0];
    const int*   ei   = (const int*)d_in[1];
    const float* Wq   = (const float*)d_in[2];
    const float* bq   = (const float*)d_in[3];
    const float* Wk   = (const float*)d_in[4];
    const float* bk   = (const float*)d_in[5];
    const float* Wv   = (const float*)d_in[6];
    const float* bv   = (const float*)d_in[7];
    const float* ln_g = (const float*)d_in[8];
    const float* ln_b = (const float*)d_in[9];
    const float* W1   = (const float*)d_in[10];
    const float* b1   = (const float*)d_in[11];
    const float* W2   = (const float*)d_in[12];
    const float* b2   = (const float*)d_in[13];
    float* out = (float*)d_out;

    const int D = 128;
    const int N = in_sizes[0] / D;
    const int E = in_sizes[1] / 2;
    const int* src = ei;
    const int* dst = ei + E;

    const size_t ND = (size_t)N * D;
    unsigned short* qb  = (unsigned short*)d_ws;          // N*128 bf16
    unsigned char*  kvh = (unsigned char*)(qb + ND);      // N*256 fp8
    float*          hb  = (float*)(kvh + (size_t)N * 256);// N*128 fp32
    unsigned short* hnb = (unsigned short*)(hb + ND);     // N*128 bf16
    unsigned short* wcat = hnb + ND;                      // 3*16384
    unsigned short* w1t  = wcat + 49152;                  // 32768
    unsigned short* w2t  = w1t + 32768;                   // 32768
    float* bcat = (float*)(w2t + 32768);                  // 768 floats
    int* cnt   = (int*)(bcat + 768);                      // N ints (degree)
    int* slots = cnt + N;                                 // N*64 ints

    const int nprep = (49152 + 65536 + 768 + 255) / 256;  // 451
    const int rt64  = (N + 63) / 64;     // 782
    const int nseg  = (N + 7) / 8;       // 6250 nodes per XCD range
    const int nbpr  = 49;                // scatter blocks per range (512 thr)
    const int nscat = 8 * nbpr;          // 392 (%8==0 -> XCD map clean)

    // 1) weight prep + cnt zeroing
    prep_kernel<<<nprep, 256, 0, stream>>>(Wq, Wk, Wv, W1, W2,
                                           bq, bk, bv, b1, b2,
                                           wcat, w1t, w2t, bcat, cnt, N);
    // 2) merged QKV projection + slotted scatter (qkv first, scatter tail)
    scatter_qkv_kernel<<<rt64 + nscat, 512, 0, stream>>>(
        x, wcat, bcat, qb, kvh, N, src, dst, cnt, slots, E, nseg, nbpr, rt64);
    // 3) attention + residual + LN (packed-f32 edge accumulate)
    attn_ln_kernel<<<(N + 3) / 4, 256, 0, stream>>>(qb, kvh, x, cnt, slots,
                                                    ln_g, ln_b, hb, hnb, N);
    // 4) fused FFN (up + gelu + down + residual), h1 in LDS
    ffn_fused_kernel<<<rt64, 512, 0, stream>>>(hnb, w1t, w2t, bcat, hb, out, N);
}

// Round 15
// 231.913 us; speedup vs baseline: 1.0729x; 1.0729x over previous
//
#include <hip/hip_runtime.h>
#include <cmath>

// ---------------------------------------------------------------------------
// StructuralAttentionLayer on MI355X (gfx950)
// N=50000, E=800000, D=128, H=8, DK=16
// Round 22: exact restore of R19 (proven best, 236.3us). R21 falsified the
// block-order swap: latency-bound scatter blocks MUST dispatch first so
// MFMA-bound qkv blocks backfill under their stalls (qkv-first = +16us tail
// serialization). Slot-line re-writeback (~29MB) is intrinsic to single-pass
// atomic scatter (nt-hints failed both directions, order swap failed).
// Ledger final: no nt hints; scatter-first merged dispatch; amortized prep;
// packed-f32 attn; plain loads/stores; 4 dispatches (~19us gap each).
// ---------------------------------------------------------------------------

typedef short v8s __attribute__((ext_vector_type(8)));   // 8 bf16 (4 VGPRs)
typedef float v4f __attribute__((ext_vector_type(4)));   // 4 fp32 acc
typedef float v2f __attribute__((ext_vector_type(2)));

__device__ __forceinline__ float gelu_exact(float x) {
    return 0.5f * x * (1.0f + erff(x * 0.70710678118654752440f));
}

__device__ __forceinline__ unsigned short f2bf(float f) {
    unsigned int u = __float_as_uint(f);
    u = (u + 0x7fffu + ((u >> 16) & 1u)) >> 16;
    return (unsigned short)u;
}

__device__ __forceinline__ float2 bf2_to_f2(unsigned int u) {
    float2 r;
    r.x = __uint_as_float(u << 16);
    r.y = __uint_as_float(u & 0xffff0000u);
    return r;
}

__device__ __forceinline__ unsigned char f2fp8(float f) {
    unsigned int p = __builtin_amdgcn_cvt_pk_fp8_f32(f, f, 0, false);
    return (unsigned char)(p & 0xffu);
}

// per-edge attention accumulate, packed-f32 (q pre-scaled by 1/sqrt(dk))
__device__ __forceinline__ void edge_accum(uint4 k4, uint4 v4, bool ok,
                                           const v2f (&qv)[8],
                                           v2f (&acc)[8], float& sml) {
    v2f f;
    v2f da = (v2f){0.f, 0.f}, db = (v2f){0.f, 0.f};
    f = __builtin_amdgcn_cvt_pk_f32_fp8(k4.x, false); da = __builtin_elementwise_fma(f, qv[0], da);
    f = __builtin_amdgcn_cvt_pk_f32_fp8(k4.x, true);  db = __builtin_elementwise_fma(f, qv[1], db);
    f = __builtin_amdgcn_cvt_pk_f32_fp8(k4.y, false); da = __builtin_elementwise_fma(f, qv[2], da);
    f = __builtin_amdgcn_cvt_pk_f32_fp8(k4.y, true);  db = __builtin_elementwise_fma(f, qv[3], db);
    f = __builtin_amdgcn_cvt_pk_f32_fp8(k4.z, false); da = __builtin_elementwise_fma(f, qv[4], da);
    f = __builtin_amdgcn_cvt_pk_f32_fp8(k4.z, true);  db = __builtin_elementwise_fma(f, qv[5], db);
    f = __builtin_amdgcn_cvt_pk_f32_fp8(k4.w, false); da = __builtin_elementwise_fma(f, qv[6], da);
    f = __builtin_amdgcn_cvt_pk_f32_fp8(k4.w, true);  db = __builtin_elementwise_fma(f, qv[7], db);
    float dot = (da[0] + db[0]) + (da[1] + db[1]);
    float pe = ok ? __expf(dot) : 0.f;
    sml += pe;
    v2f pv = (v2f){pe, pe};
    f = __builtin_amdgcn_cvt_pk_f32_fp8(v4.x, false); acc[0] = __builtin_elementwise_fma(pv, f, acc[0]);
    f = __builtin_amdgcn_cvt_pk_f32_fp8(v4.x, true);  acc[1] = __builtin_elementwise_fma(pv, f, acc[1]);
    f = __builtin_amdgcn_cvt_pk_f32_fp8(v4.y, false); acc[2] = __builtin_elementwise_fma(pv, f, acc[2]);
    f = __builtin_amdgcn_cvt_pk_f32_fp8(v4.y, true);  acc[3] = __builtin_elementwise_fma(pv, f, acc[3]);
    f = __builtin_amdgcn_cvt_pk_f32_fp8(v4.z, false); acc[4] = __builtin_elementwise_fma(pv, f, acc[4]);
    f = __builtin_amdgcn_cvt_pk_f32_fp8(v4.z, true);  acc[5] = __builtin_elementwise_fma(pv, f, acc[5]);
    f = __builtin_amdgcn_cvt_pk_f32_fp8(v4.w, false); acc[6] = __builtin_elementwise_fma(pv, f, acc[6]);
    f = __builtin_amdgcn_cvt_pk_f32_fp8(v4.w, true);  acc[7] = __builtin_elementwise_fma(pv, f, acc[7]);
}

// ---- weight prep + cnt zeroing ---------------------------------------------

__global__ __launch_bounds__(256)
void prep_kernel(const float* __restrict__ Wq, const float* __restrict__ Wk,
                 const float* __restrict__ Wv, const float* __restrict__ W1,
                 const float* __restrict__ W2,
                 const float* __restrict__ bq, const float* __restrict__ bk,
                 const float* __restrict__ bv, const float* __restrict__ b1,
                 const float* __restrict__ b2,
                 unsigned short* __restrict__ wcat, unsigned short* __restrict__ w1t,
                 unsigned short* __restrict__ w2t, float* __restrict__ bcat,
                 int* __restrict__ cnt, int n) {
    int i = blockIdx.x * 256 + threadIdx.x;
    if (i < n) cnt[i] = 0;
    if (i < 49152) {                       // 3 x 128x128: Wt[c][k] = W[k][c]
        int m = i >> 14, j = i & 16383;
        int c = j >> 7, k = j & 127;
        const float* W = (m == 0) ? Wq : (m == 1) ? Wk : Wv;
        wcat[i] = f2bf(W[k * 128 + c]);
    } else if (i < 49152 + 32768) {        // W1: [256 cols x 128 k]
        int j = i - 49152;
        int c = j >> 7, k = j & 127;
        w1t[j] = f2bf(W1[k * 256 + c]);
    } else if (i < 49152 + 65536) {        // W2: [128 cols x 256 k]
        int j = i - 49152 - 32768;
        int c = j >> 8, k = j & 255;
        w2t[j] = f2bf(W2[k * 128 + c]);
    } else if (i < 49152 + 65536 + 768) {
        int j = i - 49152 - 65536;
        float v;
        if (j < 128)      v = bq[j];
        else if (j < 256) v = bk[j - 128];
        else if (j < 384) v = bv[j - 256];
        else if (j < 640) v = b1[j - 384];
        else              v = b2[j - 640];
        bcat[j] = v;
    }
}

// ---- merged scatter + QKV GEMM (one dispatch, scatter blocks FIRST) --------
// Blocks [0, nscat): XCD-binned slotted scatter (latency-bound, dispatches
// first so MFMA-bound qkv blocks backfill under its stalls). [nscat,..): QKV.

__global__ __launch_bounds__(512)
void scatter_qkv_kernel(const float* __restrict__ A,
                        const unsigned short* __restrict__ wcat,
                        const float* __restrict__ bcat,
                        unsigned short* __restrict__ qb,
                        unsigned char* __restrict__ kvh,
                        int n_rows,
                        const int* __restrict__ src, const int* __restrict__ dst,
                        int* __restrict__ cnt, int* __restrict__ slots,
                        int E, int nseg, int nbpr, int nscat) {
    __shared__ unsigned short Xs[8192];   // 16 KB, swizzled [64][16 chunks]

    if ((int)blockIdx.x < nscat) {
        const int r = blockIdx.x & 7;
        const int b = blockIdx.x >> 3;
        const int lo = r * nseg, hi = lo + nseg;
        const int stride = nbpr * 512;
        const int E4 = E >> 2;
        for (int i = b * 512 + threadIdx.x; i < E4; i += stride) {
            int4 d4 = ((const int4*)dst)[i];
            int4 s4 = ((const int4*)src)[i];
            if (d4.x >= lo && d4.x < hi) { int p = atomicAdd(&cnt[d4.x], 1); if (p < 64) slots[(d4.x << 6) + p] = s4.x; }
            if (d4.y >= lo && d4.y < hi) { int p = atomicAdd(&cnt[d4.y], 1); if (p < 64) slots[(d4.y << 6) + p] = s4.y; }
            if (d4.z >= lo && d4.z < hi) { int p = atomicAdd(&cnt[d4.z], 1); if (p < 64) slots[(d4.z << 6) + p] = s4.z; }
            if (d4.w >= lo && d4.w < hi) { int p = atomicAdd(&cnt[d4.w], 1); if (p < 64) slots[(d4.w << 6) + p] = s4.w; }
        }
        if (b == 0) {
            for (int e = (E4 << 2) + threadIdx.x; e < E; e += 512) {
                int d = dst[e];
                if (d >= lo && d < hi) {
                    int p = atomicAdd(&cnt[d], 1);
                    if (p < 64) slots[(d << 6) + p] = src[e];
                }
            }
        }
        return;
    }

    const int t = threadIdx.x;
    const int l = t & 63;
    const int w = t >> 6;           // wave 0..7 -> output cols [w*16, w*16+16)
    const int lq = l >> 4;          // quarter 0..3
    const int lc = l & 15;
    const int rb = (blockIdx.x - nscat) * 64;

    #pragma unroll
    for (int it = 0; it < 2; ++it) {
        int idx = it * 512 + t;             // 0..1023 v8s slots
        int row = idx >> 4, ch = idx & 15;
        v8s av = (v8s){0, 0, 0, 0, 0, 0, 0, 0};
        if (rb + row < n_rows) {
            const float* ap = &A[(size_t)(rb + row) * 128 + ch * 8];
            float4 f0 = *(const float4*)ap;
            float4 f1 = *(const float4*)(ap + 4);
            av[0] = (short)f2bf(f0.x); av[1] = (short)f2bf(f0.y);
            av[2] = (short)f2bf(f0.z); av[3] = (short)f2bf(f0.w);
            av[4] = (short)f2bf(f1.x); av[5] = (short)f2bf(f1.y);
            av[6] = (short)f2bf(f1.z); av[7] = (short)f2bf(f1.w);
        }
        *(v8s*)&Xs[row * 128 + ((ch ^ (row & 7)) * 8)] = av;
    }
    __syncthreads();

    v8s a[4][4];
    #pragma unroll
    for (int c = 0; c < 4; ++c)
        #pragma unroll
        for (int i = 0; i < 4; ++i)
            a[c][i] = *(const v8s*)&Xs[(i * 16 + lc) * 128 +
                                       (((c * 4 + lq) ^ (lc & 7)) * 8)];

    const int col = w * 16 + lc;
    #pragma unroll
    for (int y = 0; y < 3; ++y) {
        const unsigned short* Bt = wcat + y * 16384;
        v8s bf[4];
        #pragma unroll
        for (int c = 0; c < 4; ++c)
            bf[c] = *(const v8s*)&Bt[(size_t)col * 128 + c * 32 + lq * 8];

        v4f acc[4];
        #pragma unroll
        for (int i = 0; i < 4; ++i) acc[i] = (v4f){0.f, 0.f, 0.f, 0.f};
        #pragma unroll
        for (int c = 0; c < 4; ++c)
            #pragma unroll
            for (int i = 0; i < 4; ++i)
                acc[i] = __builtin_amdgcn_mfma_f32_16x16x32_bf16(a[c][i], bf[c], acc[i], 0, 0, 0);

        float bi = bcat[y * 128 + col];
        #pragma unroll
        for (int i = 0; i < 4; ++i) {
            #pragma unroll
            for (int reg = 0; reg < 4; ++reg) {
                int rr = rb + i * 16 + lq * 4 + reg;
                if (rr >= n_rows) continue;
                float vv = acc[i][reg] + bi;
                if (y == 0)
                    qb[(size_t)rr * 128 + col] = f2bf(vv);
                else
                    kvh[(size_t)rr * 256 + w * 32 + lc + (y == 2 ? 16 : 0)] = f2fp8(vv);
            }
        }
    }
}

// ---- Attention + residual + LayerNorm --------------------------------------

__global__ __launch_bounds__(256)
void attn_ln_kernel(const unsigned short* __restrict__ q,
                    const unsigned char* __restrict__ kvh,
                    const float* __restrict__ x,
                    const int* __restrict__ cnt, const int* __restrict__ slots,
                    const float* __restrict__ ln_g, const float* __restrict__ ln_b,
                    float* __restrict__ hb, unsigned short* __restrict__ hnb,
                    int n) {
    const int wave = threadIdx.x >> 6;
    const int lane = threadIdx.x & 63;
    const int node = blockIdx.x * 4 + wave;
    if (node >= n) return;
    const int head = lane & 7;
    const int slot = lane >> 3;

    const unsigned int* qp = (const unsigned int*)&q[(size_t)node * 128 + head * 16];
    v2f qv[8];
    #pragma unroll
    for (int i = 0; i < 8; ++i) {
        float2 r = bf2_to_f2(qp[i]);
        qv[i] = (v2f){r.x * 0.25f, r.y * 0.25f};
    }

    const int e0 = node << 6;
    const int e1 = e0 + min(cnt[node], 64);

    float sml = 0.f;
    v2f acc[8];
    #pragma unroll
    for (int i = 0; i < 8; ++i) acc[i] = (v2f){0.f, 0.f};

    if (e1 > e0) {
        const int elast = e1 - 1;
        for (int j = e0; j < e1; j += 16) {
            int ea = j + slot;
            int eb = ea + 8;
            bool oka = ea < e1;
            bool okb = eb < e1;
            int sa = slots[oka ? ea : elast];
            int sb = slots[okb ? eb : elast];
            const uint4* kpa = (const uint4*)&kvh[(size_t)sa * 256 + head * 32];
            const uint4* kpb = (const uint4*)&kvh[(size_t)sb * 256 + head * 32];
            uint4 ka  = kpa[0];
            uint4 va4 = kpa[1];
            uint4 kb  = kpb[0];
            uint4 vb4 = kpb[1];
            edge_accum(ka, va4, oka, qv, acc, sml);
            edge_accum(kb, vb4, okb, qv, acc, sml);
        }
    }

    // reduce-scatter butterfly over slot bits (lane bits 3,4,5)
    const bool b0 = (slot & 1) != 0, b1 = (slot & 2) != 0, b2 = (slot & 4) != 0;
    v2f k0[4];
    #pragma unroll
    for (int j = 0; j < 4; ++j) {
        v2f snd = b0 ? acc[2 * j] : acc[2 * j + 1];
        v2f kp  = b0 ? acc[2 * j + 1] : acc[2 * j];
        snd[0] = __shfl_xor(snd[0], 8, 64);
        snd[1] = __shfl_xor(snd[1], 8, 64);
        k0[j] = kp + snd;
    }
    v2f k1[2];
    #pragma unroll
    for (int j = 0; j < 2; ++j) {
        v2f snd = b1 ? k0[2 * j] : k0[2 * j + 1];
        v2f kp  = b1 ? k0[2 * j + 1] : k0[2 * j];
        snd[0] = __shfl_xor(snd[0], 16, 64);
        snd[1] = __shfl_xor(snd[1], 16, 64);
        k1[j] = kp + snd;
    }
    {
        v2f snd = b2 ? k1[0] : k1[1];
        v2f kp  = b2 ? k1[1] : k1[0];
        snd[0] = __shfl_xor(snd[0], 32, 64);
        snd[1] = __shfl_xor(snd[1], 32, 64);
        k1[0] = kp + snd;
    }
    v2f o = k1[0];

    sml += __shfl_xor(sml, 8, 64);
    sml += __shfl_xor(sml, 16, 64);
    sml += __shfl_xor(sml, 32, 64);

    float inv = 1.f / (sml + 1e-16f);

    const int d = head * 16 + slot * 2;
    float2 xv = *(const float2*)&x[(size_t)node * 128 + d];
    float2 hv = make_float2(o[0] * inv + xv.x, o[1] * inv + xv.y);
    *(float2*)&hb[(size_t)node * 128 + d] = hv;

    float s  = hv.x + hv.y;
    float s2 = hv.x * hv.x + hv.y * hv.y;
    #pragma unroll
    for (int off = 1; off < 64; off <<= 1) {
        s  += __shfl_xor(s, off, 64);
        s2 += __shfl_xor(s2, off, 64);
    }
    float mu  = s * (1.f / 128.f);
    float var = s2 * (1.f / 128.f) - mu * mu;
    float rstd = rsqrtf(var + 1e-5f);
    float2 gv = *(const float2*)&ln_g[d];
    float2 bv = *(const float2*)&ln_b[d];
    ushort2 ob;
    ob.x = f2bf((hv.x - mu) * rstd * gv.x + bv.x);
    ob.y = f2bf((hv.y - mu) * rstd * gv.y + bv.y);
    *(ushort2*)&hnb[(size_t)node * 128 + d] = ob;
}

// ---- fused FFN: out = hb + W2t^T . gelu(W1t^T . hn + b1) + b2 --------------

__global__ __launch_bounds__(512)
void ffn_fused_kernel(const unsigned short* __restrict__ hnb,
                      const unsigned short* __restrict__ w1t,
                      const unsigned short* __restrict__ w2t,
                      const float* __restrict__ bcat,
                      const float* __restrict__ hb,
                      float* __restrict__ out, int n_rows) {
    __shared__ unsigned short As[8192];    // hn tile [64][128] bf16, 16 KB
    __shared__ unsigned short H1[16384];   // h1 tile [64][256] bf16, 32 KB

    const int t = threadIdx.x;
    const int l = t & 63;
    const int w = t >> 6;
    const int lq = l >> 4;
    const int lc = l & 15;
    const int rb = blockIdx.x * 64;

    // stage hn tile coalesced -> swizzled LDS
    #pragma unroll
    for (int it = 0; it < 2; ++it) {
        int idx = it * 512 + t;
        int row = idx >> 4, ch = idx & 15;
        v8s av = (v8s){0, 0, 0, 0, 0, 0, 0, 0};
        if (rb + row < n_rows)
            av = *(const v8s*)&hnb[(size_t)(rb + row) * 128 + ch * 8];
        *(v8s*)&As[row * 128 + ((ch ^ (row & 7)) * 8)] = av;
    }

    // B1 frags for this wave's 32 mids (issued before barrier: overlaps stage)
    v8s b1f[2][4];
    #pragma unroll
    for (int j = 0; j < 2; ++j)
        #pragma unroll
        for (int c = 0; c < 4; ++c) {
            int colm = w * 32 + j * 16 + lc;
            b1f[j][c] = *(const v8s*)&w1t[(size_t)colm * 128 + c * 32 + lq * 8];
        }
    __syncthreads();

    // ---- GEMM1: 64 rows x 32 mids ----
    v4f acc1[4][2];
    #pragma unroll
    for (int i = 0; i < 4; ++i)
        #pragma unroll
        for (int j = 0; j < 2; ++j)
            acc1[i][j] = (v4f){0.f, 0.f, 0.f, 0.f};

    #pragma unroll
    for (int c = 0; c < 4; ++c) {
        v8s a[4];
        #pragma unroll
        for (int i = 0; i < 4; ++i)
            a[i] = *(const v8s*)&As[(i * 16 + lc) * 128 +
                                    (((c * 4 + lq) ^ (lc & 7)) * 8)];
        #pragma unroll
        for (int i = 0; i < 4; ++i)
            #pragma unroll
            for (int j = 0; j < 2; ++j)
                acc1[i][j] = __builtin_amdgcn_mfma_f32_16x16x32_bf16(a[i], b1f[j][c], acc1[i][j], 0, 0, 0);
    }

    // bias + gelu -> h1 LDS (swizzled scalar bf16 writes)
    #pragma unroll
    for (int j = 0; j < 2; ++j) {
        int colm = w * 32 + j * 16 + lc;
        float bi = bcat[384 + colm];
        int ch = colm >> 3;
        #pragma unroll
        for (int i = 0; i < 4; ++i) {
            #pragma unroll
            for (int reg = 0; reg < 4; ++reg) {
                int r = i * 16 + lq * 4 + reg;
                float vv = gelu_exact(acc1[i][j][reg] + bi);
                H1[r * 256 + ((ch ^ (r & 7)) * 8) + (colm & 7)] = f2bf(vv);
            }
        }
    }

    // B2 frags for this wave's 16 out cols (issue before barrier)
    const int col = w * 16 + lc;
    v8s b2f[8];
    #pragma unroll
    for (int c = 0; c < 8; ++c)
        b2f[c] = *(const v8s*)&w2t[(size_t)col * 256 + c * 32 + lq * 8];
    __syncthreads();

    // ---- GEMM2: 64 rows x 16 cols, K=256 from h1 LDS ----
    v4f acc2[4];
    #pragma unroll
    for (int i = 0; i < 4; ++i) acc2[i] = (v4f){0.f, 0.f, 0.f, 0.f};

    #pragma unroll
    for (int c = 0; c < 8; ++c) {
        #pragma unroll
        for (int i = 0; i < 4; ++i) {
            v8s a = *(const v8s*)&H1[(i * 16 + lc) * 256 +
                                     (((c * 4 + lq) ^ (lc & 7)) * 8)];
            acc2[i] = __builtin_amdgcn_mfma_f32_16x16x32_bf16(a, b2f[c], acc2[i], 0, 0, 0);
        }
    }

    float bi2 = bcat[640 + col];
    #pragma unroll
    for (int i = 0; i < 4; ++i) {
        #pragma unroll
        for (int reg = 0; reg < 4; ++reg) {
            int rr = rb + i * 16 + lq * 4 + reg;
            if (rr >= n_rows) continue;
            out[(size_t)rr * 128 + col] =
                acc2[i][reg] + bi2 + hb[(size_t)rr * 128 + col];
        }
    }
}

// ---------------------------------------------------------------------------

extern "C" void kernel_launch(void* const* d_in, const int* in_sizes, int n_in,
                              void* d_out, int out_size, void* d_ws, size_t ws_size,
                              hipStream_t stream) {
    const float* x    = (const float*)d_in[0];
    const int*   ei   = (const int*)d_in[1];
    const float* Wq   = (const float*)d_in[2];
    const float* bq   = (const float*)d_in[3];
    const float* Wk   = (const float*)d_in[4];
    const float* bk   = (const float*)d_in[5];
    const float* Wv   = (const float*)d_in[6];
    const float* bv   = (const float*)d_in[7];
    const float* ln_g = (const float*)d_in[8];
    const float* ln_b = (const float*)d_in[9];
    const float* W1   = (const float*)d_in[10];
    const float* b1   = (const float*)d_in[11];
    const float* W2   = (const float*)d_in[12];
    const float* b2   = (const float*)d_in[13];
    float* out = (float*)d_out;

    const int D = 128;
    const int N = in_sizes[0] / D;
    const int E = in_sizes[1] / 2;
    const int* src = ei;
    const int* dst = ei + E;

    const size_t ND = (size_t)N * D;
    unsigned short* qb  = (unsigned short*)d_ws;          // N*128 bf16
    unsigned char*  kvh = (unsigned char*)(qb + ND);      // N*256 fp8
    float*          hb  = (float*)(kvh + (size_t)N * 256);// N*128 fp32
    unsigned short* hnb = (unsigned short*)(hb + ND);     // N*128 bf16
    unsigned short* wcat = hnb + ND;                      // 3*16384
    unsigned short* w1t  = wcat + 49152;                  // 32768
    unsigned short* w2t  = w1t + 32768;                   // 32768
    float* bcat = (float*)(w2t + 32768);                  // 768 floats
    int* cnt   = (int*)(bcat + 768);                      // N ints (degree)
    int* slots = cnt + N;                                 // N*64 ints

    const int nprep = (49152 + 65536 + 768 + 255) / 256;  // 451
    const int rt64  = (N + 63) / 64;     // 782
    const int nseg  = (N + 7) / 8;       // 6250 nodes per XCD range
    const int nbpr  = 49;                // scatter blocks per range (512 thr)
    const int nscat = 8 * nbpr;          // 392 (%8==0 -> XCD map clean)

    // 1) weight prep + cnt zeroing
    prep_kernel<<<nprep, 256, 0, stream>>>(Wq, Wk, Wv, W1, W2,
                                           bq, bk, bv, b1, b2,
                                           wcat, w1t, w2t, bcat, cnt, N);
    // 2) merged slotted scatter + QKV projection (scatter blocks first)
    scatter_qkv_kernel<<<nscat + rt64, 512, 0, stream>>>(
        x, wcat, bcat, qb, kvh, N, src, dst, cnt, slots, E, nseg, nbpr, nscat);
    // 3) attention + residual + LN (packed-f32 edge accumulate)
    attn_ln_kernel<<<(N + 3) / 4, 256, 0, stream>>>(qb, kvh, x, cnt, slots,
                                                    ln_g, ln_b, hb, hnb, N);
    // 4) fused FFN (up + gelu + down + residual), h1 in LDS
    ffn_fused_kernel<<<rt64, 512, 0, stream>>>(hnb, w1t, w2t, bcat, hb, out, N);
}